// Round 19
// baseline (548.982 us; speedup 1.0000x reference)
//
#include <hip/hip_runtime.h>

#define B_ 2048
#define F_ 16384
#define D_ 512
#define O_ 4096

typedef __attribute__((ext_vector_type(8))) short bf16x8;
typedef __attribute__((ext_vector_type(4))) float f32x4;
typedef unsigned long long ull;

__device__ inline unsigned short f2bf(float f) {
    unsigned u = __float_as_uint(f);
    u += 0x7FFFu + ((u >> 16) & 1u);   // RNE
    return (unsigned short)(u >> 16);
}

__device__ inline void glds16(const void* g, void* l) {
    __builtin_amdgcn_global_load_lds((const __attribute__((address_space(1))) void*)g,
                                     (__attribute__((address_space(3))) void*)l, 16, 0, 0);
}

// ---------------- fp32 -> bf16 bulk convert ----------------
__global__ void cvt_bf16_kernel(const float* __restrict__ s, unsigned short* __restrict__ d, int n4) {
    int stride = gridDim.x * blockDim.x;
    for (int i = blockIdx.x * blockDim.x + threadIdx.x; i < n4; i += stride) {
        float4 v = ((const float4*)s)[i];
        ushort4 o;
        o.x = f2bf(v.x); o.y = f2bf(v.y); o.z = f2bf(v.z); o.w = f2bf(v.w);
        ((ushort4*)d)[i] = o;
    }
}

// ---------------- top-k phase 1: per-2048-chunk top-20 + bf16 emit (R15) ----------
__global__ __launch_bounds__(256) void topk1_kernel(const float* __restrict__ sae,
        ull* __restrict__ cand, unsigned short* __restrict__ sae_bf) {
    __shared__ ull maxk[256];
    __shared__ ull cbuf[160];
    int tid = threadIdx.x;
    int chunk = blockIdx.x, row = blockIdx.y;
    size_t rbase = (size_t)row * F_ + chunk * 2048;
    const float4* src4 = (const float4*)(sae + rbase);
    ushort4* dst4 = (ushort4*)(sae_bf + rbase);

    float4 va = src4[tid], vb = src4[tid + 256];
    ushort4 oa, ob;
    oa.x = f2bf(va.x); oa.y = f2bf(va.y); oa.z = f2bf(va.z); oa.w = f2bf(va.w);
    ob.x = f2bf(vb.x); ob.y = f2bf(vb.y); ob.z = f2bf(vb.z); ob.w = f2bf(vb.w);
    dst4[tid] = oa; dst4[tid + 256] = ob;

    int c0 = chunk * 2048 + 4 * tid;
#define MKKEY(v, c) ((((ull)__float_as_uint(v)) << 32) | (unsigned)(~(c)))
    ull k0 = MKKEY(va.x, c0 + 0), k1 = MKKEY(va.y, c0 + 1);
    ull k2 = MKKEY(va.z, c0 + 2), k3 = MKKEY(va.w, c0 + 3);
    ull k4 = MKKEY(vb.x, c0 + 1024), k5 = MKKEY(vb.y, c0 + 1025);
    ull k6 = MKKEY(vb.z, c0 + 1026), k7 = MKKEY(vb.w, c0 + 1027);
#undef MKKEY
#define CE(a, b) { ull x_ = a, y_ = b; ull h_ = x_ > y_ ? x_ : y_; ull l_ = x_ > y_ ? y_ : x_; a = h_; b = l_; }
    CE(k0,k1) CE(k2,k3) CE(k4,k5) CE(k6,k7)
    CE(k0,k2) CE(k1,k3) CE(k4,k6) CE(k5,k7)
    CE(k1,k2) CE(k5,k6)
    CE(k0,k4) CE(k1,k5) CE(k2,k6) CE(k3,k7)
    CE(k2,k4) CE(k3,k5)
    CE(k1,k2) CE(k3,k4) CE(k5,k6)
#undef CE

    maxk[tid] = k0;
    __syncthreads();
    int r = 0;
    for (int k = 0; k < 256; ++k) r += (maxk[k] > k0);
    if (r < 20) {
        ull* o = cbuf + r * 8;
        o[0]=k0; o[1]=k1; o[2]=k2; o[3]=k3; o[4]=k4; o[5]=k5; o[6]=k6; o[7]=k7;
    }
    __syncthreads();
    ull myc = (tid < 160) ? cbuf[tid] : 0ull;
    int r2 = 0;
    for (int k = 0; k < 160; ++k) r2 += (cbuf[k] > myc);
    if (tid < 160 && r2 < 20)
        cand[((size_t)row * 8 + chunk) * 20 + r2] = myc;
}

// ---------------- bi-interaction pooling, fused candidate rank-select ------------
__global__ __launch_bounds__(256) void bi_kernel(const ull* __restrict__ cand,
        const float* __restrict__ emb, float* __restrict__ bi) {
    __shared__ ull c[160];
    __shared__ int   si[20];
    __shared__ float sv[20];
    int tid = threadIdx.x, row = blockIdx.x;
    if (tid < 160) c[tid] = cand[(size_t)row * 160 + tid];
    __syncthreads();
    if (tid < 160) {
        ull m = c[tid];
        int r = 0;
        for (int k = 0; k < 160; ++k) r += (c[k] > m);
        if (r < 20) {
            sv[r] = __uint_as_float((unsigned)(m >> 32));
            si[r] = (int)(~(unsigned)m);
        }
    }
    __syncthreads();
    float s0 = 0.f, q0 = 0.f, s1 = 0.f, q1 = 0.f;
    int d0 = tid, d1 = tid + 256;
#pragma unroll
    for (int k = 0; k < 20; ++k) {
        float v = sv[k];
        const float* e = emb + (size_t)si[k] * D_;
        float e0 = e[d0], e1 = e[d1];
        s0 += v * e0; q0 += v * v * e0 * e0;
        s1 += v * e1; q1 += v * v * e1 * e1;
    }
    bi[(size_t)row * D_ + d0] = 0.5f * (s0 * s0 - q0);
    bi[(size_t)row * D_ + d1] = 0.5f * (s1 * s1 - q1);
}

// ---------------- coalesced column stats, stage 1: per-row-band partials ----------
__global__ __launch_bounds__(256) void colpart_kernel(const float* __restrict__ X,
        float* __restrict__ ps, float* __restrict__ pq, int N) {
    __shared__ float4 ls[128], lq[128];
    int tid = threadIdx.x;
    int c4 = tid & 127, half = tid >> 7;
    int r0 = blockIdx.x * 32 + half;
    float4 s = {0.f, 0.f, 0.f, 0.f}, q = {0.f, 0.f, 0.f, 0.f};
#pragma unroll
    for (int i = 0; i < 16; ++i) {
        float4 x = ((const float4*)(X + (size_t)(r0 + 2 * i) * N))[c4];
        s.x += x.x; s.y += x.y; s.z += x.z; s.w += x.w;
        q.x += x.x * x.x; q.y += x.y * x.y; q.z += x.z * x.z; q.w += x.w * x.w;
    }
    if (half) { ls[c4] = s; lq[c4] = q; }
    __syncthreads();
    if (!half) {
        float4 s2 = ls[c4], q2 = lq[c4];
        s.x += s2.x; s.y += s2.y; s.z += s2.z; s.w += s2.w;
        q.x += q2.x; q.y += q2.y; q.z += q2.z; q.w += q2.w;
        ((float4*)(ps + (size_t)blockIdx.x * N))[c4] = s;
        ((float4*)(pq + (size_t)blockIdx.x * N))[c4] = q;
    }
}

// ---------------- column stats, stage 2: reduce partials -> scale/shift ----------
__global__ __launch_bounds__(256) void colfin_kernel(const float* __restrict__ ps,
        const float* __restrict__ pq, const float* __restrict__ gamma,
        const float* __restrict__ beta, float* __restrict__ scale,
        float* __restrict__ shift, int npart, int N, int M) {
    int col = blockIdx.x * 256 + threadIdx.x;
    if (col >= N) return;
    float s = 0.f, q = 0.f;
    for (int k = 0; k < npart; ++k) {
        s += ps[(size_t)k * N + col];
        q += pq[(size_t)k * N + col];
    }
    float mean = s / M;
    float var = q / M - mean * mean;
    float sc = gamma[col] * rsqrtf(var + 1e-5f);
    scale[col] = sc;
    shift[col] = beta[col] - mean * sc;
}

// ---------------- apply BN (+ optional relu), emit bf16 ----------------
__global__ void bn_apply_kernel(const float* __restrict__ X, const float* __restrict__ scale,
        const float* __restrict__ shift, unsigned short* __restrict__ Y,
        int n4, int colmask4, int relu) {
    int stride = gridDim.x * blockDim.x;
    for (int i = blockIdx.x * blockDim.x + threadIdx.x; i < n4; i += stride) {
        float4 x = ((const float4*)X)[i];
        int c = (i & colmask4) * 4;
        float4 sc = *(const float4*)(scale + c);
        float4 sh = *(const float4*)(shift + c);
        float y0 = x.x * sc.x + sh.x;
        float y1 = x.y * sc.y + sh.y;
        float y2 = x.z * sc.z + sh.z;
        float y3 = x.w * sc.w + sh.w;
        if (relu) {
            y0 = fmaxf(y0, 0.f); y1 = fmaxf(y1, 0.f);
            y2 = fmaxf(y2, 0.f); y3 = fmaxf(y3, 0.f);
        }
        ushort4 o;
        o.x = f2bf(y0); o.y = f2bf(y1); o.z = f2bf(y2); o.w = f2bf(y3);
        ((ushort4*)Y)[i] = o;
    }
}

// ---------------- bf16 GEMM: 8-wave, swizzled LDS, frag-double-buffered (R8/R15) --
// Used for gemm1 only now.
template <bool FUSE>
__global__ __launch_bounds__(512) void gemm8w_kernel(const unsigned short* __restrict__ A,
        const unsigned short* __restrict__ W, const float* __restrict__ bias,
        float* __restrict__ out, const float* __restrict__ lin,
        const float* __restrict__ gb, float* __restrict__ out0,
        int M, int N, int K) {
    __shared__ short As[3 * 4096];
    __shared__ short Bs[3 * 4096];
    int tid = threadIdx.x;
    int lane = tid & 63, w = tid >> 6;
    int wr = w >> 2, wc = w & 3;
    int l15 = lane & 15, lhi = lane >> 4;
    int xk = (l15 >> 1) & 3;
    int rchunk = (lhi ^ xk) << 3;

    int nwg = gridDim.x * gridDim.y;
    int bid = blockIdx.y * gridDim.x + blockIdx.x;
    int s = (bid & 7) * (nwg >> 3) + (bid >> 3);
    int gsz = gridDim.x << 3;
    int g = s / gsz, r = s % gsz;
    int by = (g << 3) + (r & 7);
    int bx = r >> 3;
    int bm = by * 128, bn = bx * 128;

    int rA = tid >> 2;
    int kp = tid & 3;
    int kps = kp ^ ((rA >> 1) & 3);
    const unsigned short* gA = A + (size_t)(bm + rA) * K + kps * 8;
    const unsigned short* gB = W + (size_t)(bn + rA) * K + kps * 8;

    f32x4 acc[4][2];
#pragma unroll
    for (int i = 0; i < 4; ++i)
#pragma unroll
        for (int j = 0; j < 2; ++j) { f32x4 z = {0.f, 0.f, 0.f, 0.f}; acc[i][j] = z; }

    auto STAGE = [&](int t, int buf) {
        int k0 = t << 5;
        glds16(gA + k0, (char*)(As + buf * 4096) + w * 1024);
        glds16(gB + k0, (char*)(Bs + buf * 4096) + w * 1024);
    };
    auto LOADF = [&](bf16x8* af, bf16x8* bv, int buf) {
        const short* Ab = As + buf * 4096;
        const short* Bb = Bs + buf * 4096;
#pragma unroll
        for (int mi = 0; mi < 4; ++mi)
            af[mi] = *(const bf16x8*)&Ab[(wr * 64 + mi * 16 + l15) * 32 + rchunk];
#pragma unroll
        for (int ni = 0; ni < 2; ++ni)
            bv[ni] = *(const bf16x8*)&Bb[(wc * 32 + ni * 16 + l15) * 32 + rchunk];
    };
    auto MFMA8 = [&](const bf16x8* af, const bf16x8* bv) {
#pragma unroll
        for (int mi = 0; mi < 4; ++mi)
#pragma unroll
            for (int ni = 0; ni < 2; ++ni)
                acc[mi][ni] = __builtin_amdgcn_mfma_f32_16x16x32_bf16(af[mi], bv[ni], acc[mi][ni], 0, 0, 0);
    };

    int NT = K >> 5;

    STAGE(0, 0);
    STAGE(1, 1);
    asm volatile("s_waitcnt vmcnt(2)" ::: "memory");
    __builtin_amdgcn_sched_barrier(0);
    __builtin_amdgcn_s_barrier();
    __builtin_amdgcn_sched_barrier(0);

    bf16x8 afA[4], bvA[2], afB[4], bvB[2];
    LOADF(afA, bvA, 0);

    for (int t = 0; t + 4 <= NT; t += 2) {
        STAGE(t + 2, (t + 2) % 3);
        asm volatile("s_waitcnt lgkmcnt(0)" ::: "memory");
        __builtin_amdgcn_sched_barrier(0);
        asm volatile("s_waitcnt vmcnt(2)" ::: "memory");
        __builtin_amdgcn_sched_barrier(0);
        __builtin_amdgcn_s_barrier();
        __builtin_amdgcn_sched_barrier(0);
        LOADF(afB, bvB, (t + 1) % 3);
        __builtin_amdgcn_s_setprio(1);
        MFMA8(afA, bvA);
        __builtin_amdgcn_s_setprio(0);
        __builtin_amdgcn_sched_group_barrier(0x100, 6, 0);
        __builtin_amdgcn_sched_group_barrier(0x008, 8, 0);
        STAGE(t + 3, (t + 3) % 3);
        asm volatile("s_waitcnt lgkmcnt(0)" ::: "memory");
        __builtin_amdgcn_sched_barrier(0);
        asm volatile("s_waitcnt vmcnt(2)" ::: "memory");
        __builtin_amdgcn_sched_barrier(0);
        __builtin_amdgcn_s_barrier();
        __builtin_amdgcn_sched_barrier(0);
        LOADF(afA, bvA, (t + 2) % 3);
        __builtin_amdgcn_s_setprio(1);
        MFMA8(afB, bvB);
        __builtin_amdgcn_s_setprio(0);
        __builtin_amdgcn_sched_group_barrier(0x100, 6, 0);
        __builtin_amdgcn_sched_group_barrier(0x008, 8, 0);
    }
    asm volatile("s_waitcnt lgkmcnt(0)" ::: "memory");
    __builtin_amdgcn_sched_barrier(0);
    asm volatile("s_waitcnt vmcnt(0)" ::: "memory");
    __builtin_amdgcn_sched_barrier(0);
    __builtin_amdgcn_s_barrier();
    __builtin_amdgcn_sched_barrier(0);
    LOADF(afB, bvB, (NT - 1) % 3);
    __builtin_amdgcn_s_setprio(1);
    MFMA8(afA, bvA);
    __builtin_amdgcn_s_setprio(0);
    asm volatile("s_waitcnt lgkmcnt(0)" ::: "memory");
    __builtin_amdgcn_sched_barrier(0);
    __builtin_amdgcn_s_setprio(1);
    MFMA8(afB, bvB);
    __builtin_amdgcn_s_setprio(0);

#pragma unroll
    for (int mi = 0; mi < 4; ++mi)
#pragma unroll
        for (int ni = 0; ni < 2; ++ni) {
            int col = bn + wc * 32 + ni * 16 + l15;
            float bb = bias[col];
            float gbv = FUSE ? gb[col] : 0.f;
            int row0 = bm + wr * 64 + mi * 16 + lhi * 4;
#pragma unroll
            for (int r2 = 0; r2 < 4; ++r2) {
                size_t idx = (size_t)(row0 + r2) * N + col;
                float v = acc[mi][ni][r2] + bb;
                out[idx] = v;
                if (FUSE) out0[idx] = gbv + lin[idx] + v;
            }
        }
}

// ---------------- 256x128 GEMM: 1-barrier iter, 4 counted-lgkm waypoints ---------
// Geometry/swizzle/epilogue verified (R16-R18, conflicts==0). R19: reads issued in
// 4 groups; MFMA starts at lgkm(12) instead of lgkm(8)-after-16-reads. DS ops
// complete in order -> counted lgkm waypoints are exact.
// FUSE: epilogue also writes out0 = gb[col] + lin[idx] + (acc+bias).
template <bool FUSE>
__global__ __launch_bounds__(512) void gemm256_kernel(const unsigned short* __restrict__ A,
        const unsigned short* __restrict__ W, const float* __restrict__ bias,
        float* __restrict__ out, const float* __restrict__ lin,
        const float* __restrict__ gb, float* __restrict__ out0,
        int M, int N, int K) {
    __shared__ short As[3 * 16384];   // 3 x 256x64 = 96 KB
    __shared__ short Bs[3 * 8192];    // 3 x 128x64 = 48 KB
    int tid = threadIdx.x;
    int l = tid & 63, w = tid >> 6;
    int wm = w >> 1, wn = w & 1;
    int l15 = l & 15, lhi = l >> 4;
    int lr = l >> 3, lc = l & 7;
    int sc = lc ^ lr;                     // pre-swizzled source chunk

    int bid = blockIdx.y * gridDim.x + blockIdx.x;
    int s = (bid & 7) * ((gridDim.x * gridDim.y) >> 3) + (bid >> 3);
    int by = s & 7, bx = s >> 3;
    int bm = by * 256, bn = bx * 128;

    const unsigned short* gA0 = A + (size_t)(bm +   0 + w * 8 + lr) * K + sc * 8;
    const unsigned short* gA1 = A + (size_t)(bm +  64 + w * 8 + lr) * K + sc * 8;
    const unsigned short* gA2 = A + (size_t)(bm + 128 + w * 8 + lr) * K + sc * 8;
    const unsigned short* gA3 = A + (size_t)(bm + 192 + w * 8 + lr) * K + sc * 8;
    const unsigned short* gB0 = W + (size_t)(bn +   0 + w * 8 + lr) * K + sc * 8;
    const unsigned short* gB1 = W + (size_t)(bn +  64 + w * 8 + lr) * K + sc * 8;

    int xk7 = l15 & 7;
    int aR0 = (wm * 64 +  0 + l15) << 7;
    int aR1 = (wm * 64 + 16 + l15) << 7;
    int aR2 = (wm * 64 + 32 + l15) << 7;
    int aR3 = (wm * 64 + 48 + l15) << 7;
    int bR0 = (wn * 64 +  0 + l15) << 7;
    int bR1 = (wn * 64 + 16 + l15) << 7;
    int bR2 = (wn * 64 + 32 + l15) << 7;
    int bR3 = (wn * 64 + 48 + l15) << 7;
    int c0 = ((0 + lhi) ^ xk7) << 4;
    int c1 = ((4 + lhi) ^ xk7) << 4;

    f32x4 acc[4][4];
#pragma unroll
    for (int i = 0; i < 4; ++i)
#pragma unroll
        for (int j = 0; j < 4; ++j) { f32x4 z = {0.f, 0.f, 0.f, 0.f}; acc[i][j] = z; }

    const char* AsB = (const char*)As;
    const char* BsB = (const char*)Bs;
#define RDA(rr, cc, bo) (*(const bf16x8*)(AsB + (bo) + (rr) + (cc)))
#define RDB(rr, cc, bo) (*(const bf16x8*)(BsB + (bo) + (rr) + (cc)))
#define MM(x, y, ai, bi_) acc[ai][bi_] = __builtin_amdgcn_mfma_f32_16x16x32_bf16(x, y, acc[ai][bi_], 0, 0, 0);

    bf16x8 a0, a1, a2, a3, b0, b1, b2, b3;       // ksub0 frags
    bf16x8 a4, a5, a6, a7, b4, b5, b6, b7;       // ksub1 frags
#define SB    __builtin_amdgcn_sched_barrier(0);
#define BAR   { __builtin_amdgcn_s_barrier(); SB }

    int NT = K >> 6;

    // prologue: stage tiles 0,1
    {
        int dA = w * 1024;
        glds16(gA0, (char*)As + dA);           glds16(gA1, (char*)As + 8192 + dA);
        glds16(gA2, (char*)As + 16384 + dA);   glds16(gA3, (char*)As + 24576 + dA);
        glds16(gB0, (char*)Bs + dA);           glds16(gB1, (char*)Bs + 8192 + dA);
        glds16(gA0 + 64, (char*)As + 32768 + dA);         glds16(gA1 + 64, (char*)As + 32768 + 8192 + dA);
        glds16(gA2 + 64, (char*)As + 32768 + 16384 + dA); glds16(gA3 + 64, (char*)As + 32768 + 24576 + dA);
        glds16(gB0 + 64, (char*)Bs + 16384 + dA);         glds16(gB1 + 64, (char*)Bs + 16384 + 8192 + dA);
    }
    asm volatile("s_waitcnt vmcnt(6)" ::: "memory");
    SB
    BAR;

    int cur = 0;
    for (int t = 0; t < NT; ++t) {
        int s2 = cur + 2; if (s2 >= 3) s2 -= 3;
        int Abo = cur * 32768, Bbo = cur * 16384;
        int AboS = s2 * 32768, BboS = s2 * 16384;
        int kst = (t + 2) << 6;
        bool st = (t + 2) < NT;
        int dA = w * 1024;

        // group 1: a0,a1,b0,b1 (ksub0)
        a0 = RDA(aR0, c0, Abo); a1 = RDA(aR1, c0, Abo);
        b0 = RDB(bR0, c0, Bbo); b1 = RDB(bR1, c0, Bbo);
        SB
        // group 2: a2,a3,b2,b3 (ksub0)
        a2 = RDA(aR2, c0, Abo); a3 = RDA(aR3, c0, Abo);
        b2 = RDB(bR2, c0, Bbo); b3 = RDB(bR3, c0, Bbo);
        SB
        // group 3: a4,a5,b4,b5 (ksub1)
        a4 = RDA(aR0, c1, Abo); a5 = RDA(aR1, c1, Abo);
        b4 = RDB(bR0, c1, Bbo); b5 = RDB(bR1, c1, Bbo);
        SB
        // group 4: a6,a7,b6,b7 (ksub1)
        a6 = RDA(aR2, c1, Abo); a7 = RDA(aR3, c1, Abo);
        b6 = RDB(bR2, c1, Bbo); b7 = RDB(bR3, c1, Bbo);
        SB
        // stage loads of tile t+2 (vmcnt only, doesn't disturb lgkm counts)
        if (st) {
            glds16(gA0 + kst, (char*)As + AboS + dA);
            glds16(gA1 + kst, (char*)As + AboS + 8192 + dA);
            glds16(gA2 + kst, (char*)As + AboS + 16384 + dA);
            glds16(gA3 + kst, (char*)As + AboS + 24576 + dA);
            glds16(gB0 + kst, (char*)Bs + BboS + dA);
            glds16(gB1 + kst, (char*)Bs + BboS + 8192 + dA);
        }
        SB
        // waypoint 1: group 1 landed (12 still outstanding)
        asm volatile("s_waitcnt lgkmcnt(12)" ::: "memory"); SB
        __builtin_amdgcn_s_setprio(1);
        MM(a0, b0, 0, 0) MM(a0, b1, 0, 1) MM(a1, b0, 1, 0) MM(a1, b1, 1, 1)
        __builtin_amdgcn_s_setprio(0); SB
        // waypoint 2: group 2 landed
        asm volatile("s_waitcnt lgkmcnt(8)" ::: "memory"); SB
        __builtin_amdgcn_s_setprio(1);
        MM(a2, b0, 2, 0) MM(a2, b1, 2, 1) MM(a3, b0, 3, 0) MM(a3, b1, 3, 1)
        MM(a0, b2, 0, 2) MM(a0, b3, 0, 3) MM(a1, b2, 1, 2) MM(a1, b3, 1, 3)
        MM(a2, b2, 2, 2) MM(a2, b3, 2, 3) MM(a3, b2, 3, 2) MM(a3, b3, 3, 3)
        __builtin_amdgcn_s_setprio(0); SB
        // waypoint 3: group 3 landed
        asm volatile("s_waitcnt lgkmcnt(4)" ::: "memory"); SB
        __builtin_amdgcn_s_setprio(1);
        MM(a4, b4, 0, 0) MM(a4, b5, 0, 1) MM(a5, b4, 1, 0) MM(a5, b5, 1, 1)
        __builtin_amdgcn_s_setprio(0); SB
        // waypoint 4: all landed
        asm volatile("s_waitcnt lgkmcnt(0)" ::: "memory"); SB
        __builtin_amdgcn_s_setprio(1);
        MM(a6, b4, 2, 0) MM(a6, b5, 2, 1) MM(a7, b4, 3, 0) MM(a7, b5, 3, 1)
        MM(a4, b6, 0, 2) MM(a4, b7, 0, 3) MM(a5, b6, 1, 2) MM(a5, b7, 1, 3)
        MM(a6, b6, 2, 2) MM(a6, b7, 2, 3) MM(a7, b6, 3, 2) MM(a7, b7, 3, 3)
        __builtin_amdgcn_s_setprio(0);
        // publish tile t+1 (counted vmcnt: t+2's 6 loads stay in flight)
        if (t + 1 < NT) {
            if (t + 2 < NT) { asm volatile("s_waitcnt vmcnt(6)" ::: "memory"); }
            else            { asm volatile("s_waitcnt vmcnt(0)" ::: "memory"); }
            SB
            BAR;
        }
        ++cur; if (cur >= 3) cur = 0;
    }
#undef RDA
#undef RDB
#undef MM
#undef SB
#undef BAR

#pragma unroll
    for (int mi = 0; mi < 4; ++mi)
#pragma unroll
        for (int ni = 0; ni < 4; ++ni) {
            int col = bn + wn * 64 + ni * 16 + l15;
            float bb = bias[col];
            float gbv = FUSE ? gb[col] : 0.f;
            int row0 = bm + wm * 64 + mi * 16 + lhi * 4;
#pragma unroll
            for (int r2 = 0; r2 < 4; ++r2) {
                size_t idx = (size_t)(row0 + r2) * N + col;
                float v = acc[mi][ni][r2] + bb;
                out[idx] = v;
                if (FUSE) out0[idx] = gbv + lin[idx] + v;
            }
        }
}

extern "C" void kernel_launch(void* const* d_in, const int* in_sizes, int n_in,
                              void* d_out, int out_size, void* d_ws, size_t ws_size,
                              hipStream_t stream) {
    const float* sae  = (const float*)d_in[0];
    const float* emb  = (const float*)d_in[1];
    const float* lin_w = (const float*)d_in[2];
    const float* lin_b = (const float*)d_in[3];
    const float* gbias = (const float*)d_in[4];
    const float* bn1g = (const float*)d_in[5];
    const float* bn1b = (const float*)d_in[6];
    const float* w1   = (const float*)d_in[7];
    const float* b1   = (const float*)d_in[8];
    const float* bn2g = (const float*)d_in[9];
    const float* bn2b = (const float*)d_in[10];
    const float* w2   = (const float*)d_in[11];
    const float* b2   = (const float*)d_in[12];
    float* out = (float*)d_out;
    const size_t BO = (size_t)B_ * O_;

    char* ws = (char*)d_ws;
    auto alloc = [&](size_t bytes) -> char* {
        char* p = ws;
        ws += (bytes + 255) & ~(size_t)255;
        return p;
    };
    unsigned short* sae_bf  = (unsigned short*)alloc((size_t)B_ * F_ * 2);  // 64 MB
    unsigned short* linw_bf = (unsigned short*)alloc((size_t)O_ * F_ * 2);  // 128 MB
    unsigned short* w1_bf   = (unsigned short*)alloc((size_t)D_ * D_ * 2);
    unsigned short* w2_bf   = (unsigned short*)alloc((size_t)O_ * D_ * 2);
    unsigned short* a1_bf   = (unsigned short*)alloc((size_t)B_ * D_ * 2);
    unsigned short* h2_bf   = (unsigned short*)alloc((size_t)B_ * D_ * 2);
    ull*   cand = (ull*)alloc((size_t)B_ * 160 * 8);
    float* bi = (float*)alloc((size_t)B_ * D_ * 4);
    float* h1 = (float*)alloc((size_t)B_ * D_ * 4);
    float* ps = (float*)alloc(64 * D_ * 4);
    float* pq = (float*)alloc(64 * D_ * 4);
    float* sc1 = (float*)alloc(D_ * 4);
    float* sh1 = (float*)alloc(D_ * 4);
    float* sc2 = (float*)alloc(D_ * 4);
    float* sh2 = (float*)alloc(D_ * 4);

    // weight conversions
    cvt_bf16_kernel<<<2048, 256, 0, stream>>>(lin_w, linw_bf, (int)((size_t)O_ * F_ / 4));
    cvt_bf16_kernel<<<256, 256, 0, stream>>>(w1, w1_bf, D_ * D_ / 4);
    cvt_bf16_kernel<<<1024, 256, 0, stream>>>(w2, w2_bf, O_ * D_ / 4);

    // top-k phase 1 (rank-select, per-chunk top-20 + sae bf16 emit)
    topk1_kernel<<<dim3(8, B_), 256, 0, stream>>>(sae, cand, sae_bf);

    // bi-interaction pooling (fused exact top-20 rank-select)
    bi_kernel<<<B_, 256, 0, stream>>>(cand, emb, bi);

    // BN1 -> bf16, GEMM1
    colpart_kernel<<<64, 256, 0, stream>>>(bi, ps, pq, D_);
    colfin_kernel<<<2, 256, 0, stream>>>(ps, pq, bn1g, bn1b, sc1, sh1, 64, D_, B_);
    bn_apply_kernel<<<1024, 256, 0, stream>>>(bi, sc1, sh1, a1_bf, B_ * D_ / 4, D_ / 4 - 1, 0);
    gemm8w_kernel<false><<<dim3(D_ / 128, B_ / 128), 512, 0, stream>>>(
        a1_bf, w1_bf, b1, h1, nullptr, nullptr, nullptr, B_, D_, D_);

    // BN2 + relu -> bf16
    colpart_kernel<<<64, 256, 0, stream>>>(h1, ps, pq, D_);
    colfin_kernel<<<2, 256, 0, stream>>>(ps, pq, bn2g, bn2b, sc2, sh2, 64, D_, B_);
    bn_apply_kernel<<<1024, 256, 0, stream>>>(h1, sc2, sh2, h2_bf, B_ * D_ / 4, D_ / 4 - 1, 1);

    // big GEMM (256x128, waypointed counted-lgkm, full K) -> linear_out (+lin_b)
    gemm256_kernel<false><<<dim3(O_ / 128, B_ / 256), 512, 0, stream>>>(
        sae_bf, linw_bf, lin_b, out + BO, nullptr, nullptr, nullptr, B_, O_, F_);

    // GEMM2 (same structure, K=512) -> interaction_out, fused final combine:
    //   out0 = global_bias + linear_out + interaction_out
    gemm256_kernel<true><<<dim3(O_ / 128, B_ / 256), 512, 0, stream>>>(
        h2_bf, w2_bf, b2, out + 2 * BO, out + BO, gbias, out, B_, O_, D_);
}

// Round 20
// 545.027 us; speedup vs baseline: 1.0073x; 1.0073x over previous
//
#include <hip/hip_runtime.h>

#define B_ 2048
#define F_ 16384
#define D_ 512
#define O_ 4096

typedef __attribute__((ext_vector_type(8))) short bf16x8;
typedef __attribute__((ext_vector_type(4))) float f32x4;
typedef unsigned long long ull;

__device__ inline unsigned short f2bf(float f) {
    unsigned u = __float_as_uint(f);
    u += 0x7FFFu + ((u >> 16) & 1u);   // RNE
    return (unsigned short)(u >> 16);
}

__device__ inline void glds16(const void* g, void* l) {
    __builtin_amdgcn_global_load_lds((const __attribute__((address_space(1))) void*)g,
                                     (__attribute__((address_space(3))) void*)l, 16, 0, 0);
}

__device__ inline void cvt_span(const float* __restrict__ s, unsigned short* __restrict__ d,
                                int n4, int tid0, int stride) {
    for (int i = tid0; i < n4; i += stride) {
        float4 v = ((const float4*)s)[i];
        ushort4 o;
        o.x = f2bf(v.x); o.y = f2bf(v.y); o.z = f2bf(v.z); o.w = f2bf(v.w);
        ((ushort4*)d)[i] = o;
    }
}

// ---------------- fused: top-k phase 1 (blocks 0..16383) + weight cvt (rest) ------
// topk1 part (R15-verified): per-2048-chunk top-20 via rank-select + sae bf16 emit.
// cvt part: grid-stride fp32->bf16 of lin_w, w1, w2. Independent memory-bound
// phases co-resident in one dispatch -> one HBM drain instead of two.
#define TOPK_BLKS (8 * B_)
#define CVT_BLKS  4096
__global__ __launch_bounds__(256) void fused_front_kernel(
        const float* __restrict__ sae, ull* __restrict__ cand,
        unsigned short* __restrict__ sae_bf,
        const float* __restrict__ lin_w, unsigned short* __restrict__ linw_bf,
        const float* __restrict__ w1, unsigned short* __restrict__ w1_bf,
        const float* __restrict__ w2, unsigned short* __restrict__ w2_bf) {
    __shared__ ull maxk[256];
    __shared__ ull cbuf[160];
    int tid = threadIdx.x;
    int bidx = blockIdx.x;
    if (bidx >= TOPK_BLKS) {
        int cb = bidx - TOPK_BLKS;
        int tid0 = cb * 256 + tid;
        int stride = CVT_BLKS * 256;
        cvt_span(lin_w, linw_bf, (int)((size_t)O_ * F_ / 4), tid0, stride);
        cvt_span(w1, w1_bf, D_ * D_ / 4, tid0, stride);
        cvt_span(w2, w2_bf, O_ * D_ / 4, tid0, stride);
        return;
    }
    int chunk = bidx & 7, row = bidx >> 3;
    size_t rbase = (size_t)row * F_ + chunk * 2048;
    const float4* src4 = (const float4*)(sae + rbase);
    ushort4* dst4 = (ushort4*)(sae_bf + rbase);

    float4 va = src4[tid], vb = src4[tid + 256];
    ushort4 oa, ob;
    oa.x = f2bf(va.x); oa.y = f2bf(va.y); oa.z = f2bf(va.z); oa.w = f2bf(va.w);
    ob.x = f2bf(vb.x); ob.y = f2bf(vb.y); ob.z = f2bf(vb.z); ob.w = f2bf(vb.w);
    dst4[tid] = oa; dst4[tid + 256] = ob;

    int c0 = chunk * 2048 + 4 * tid;
#define MKKEY(v, c) ((((ull)__float_as_uint(v)) << 32) | (unsigned)(~(c)))
    ull k0 = MKKEY(va.x, c0 + 0), k1 = MKKEY(va.y, c0 + 1);
    ull k2 = MKKEY(va.z, c0 + 2), k3 = MKKEY(va.w, c0 + 3);
    ull k4 = MKKEY(vb.x, c0 + 1024), k5 = MKKEY(vb.y, c0 + 1025);
    ull k6 = MKKEY(vb.z, c0 + 1026), k7 = MKKEY(vb.w, c0 + 1027);
#undef MKKEY
#define CE(a, b) { ull x_ = a, y_ = b; ull h_ = x_ > y_ ? x_ : y_; ull l_ = x_ > y_ ? y_ : x_; a = h_; b = l_; }
    CE(k0,k1) CE(k2,k3) CE(k4,k5) CE(k6,k7)
    CE(k0,k2) CE(k1,k3) CE(k4,k6) CE(k5,k7)
    CE(k1,k2) CE(k5,k6)
    CE(k0,k4) CE(k1,k5) CE(k2,k6) CE(k3,k7)
    CE(k2,k4) CE(k3,k5)
    CE(k1,k2) CE(k3,k4) CE(k5,k6)
#undef CE

    maxk[tid] = k0;
    __syncthreads();
    int r = 0;
    for (int k = 0; k < 256; ++k) r += (maxk[k] > k0);
    if (r < 20) {
        ull* o = cbuf + r * 8;
        o[0]=k0; o[1]=k1; o[2]=k2; o[3]=k3; o[4]=k4; o[5]=k5; o[6]=k6; o[7]=k7;
    }
    __syncthreads();
    ull myc = (tid < 160) ? cbuf[tid] : 0ull;
    int r2 = 0;
    for (int k = 0; k < 160; ++k) r2 += (cbuf[k] > myc);
    if (tid < 160 && r2 < 20)
        cand[((size_t)row * 8 + chunk) * 20 + r2] = myc;
}

// ---------------- bi-interaction pooling, fused candidate rank-select ------------
__global__ __launch_bounds__(256) void bi_kernel(const ull* __restrict__ cand,
        const float* __restrict__ emb, float* __restrict__ bi) {
    __shared__ ull c[160];
    __shared__ int   si[20];
    __shared__ float sv[20];
    int tid = threadIdx.x, row = blockIdx.x;
    if (tid < 160) c[tid] = cand[(size_t)row * 160 + tid];
    __syncthreads();
    if (tid < 160) {
        ull m = c[tid];
        int r = 0;
        for (int k = 0; k < 160; ++k) r += (c[k] > m);
        if (r < 20) {
            sv[r] = __uint_as_float((unsigned)(m >> 32));
            si[r] = (int)(~(unsigned)m);
        }
    }
    __syncthreads();
    float s0 = 0.f, q0 = 0.f, s1 = 0.f, q1 = 0.f;
    int d0 = tid, d1 = tid + 256;
#pragma unroll
    for (int k = 0; k < 20; ++k) {
        float v = sv[k];
        const float* e = emb + (size_t)si[k] * D_;
        float e0 = e[d0], e1 = e[d1];
        s0 += v * e0; q0 += v * v * e0 * e0;
        s1 += v * e1; q1 += v * v * e1 * e1;
    }
    bi[(size_t)row * D_ + d0] = 0.5f * (s0 * s0 - q0);
    bi[(size_t)row * D_ + d1] = 0.5f * (s1 * s1 - q1);
}

// ---------------- coalesced column stats, stage 1: per-row-band partials ----------
__global__ __launch_bounds__(256) void colpart_kernel(const float* __restrict__ X,
        float* __restrict__ ps, float* __restrict__ pq, int N) {
    __shared__ float4 ls[128], lq[128];
    int tid = threadIdx.x;
    int c4 = tid & 127, half = tid >> 7;
    int r0 = blockIdx.x * 32 + half;
    float4 s = {0.f, 0.f, 0.f, 0.f}, q = {0.f, 0.f, 0.f, 0.f};
#pragma unroll
    for (int i = 0; i < 16; ++i) {
        float4 x = ((const float4*)(X + (size_t)(r0 + 2 * i) * N))[c4];
        s.x += x.x; s.y += x.y; s.z += x.z; s.w += x.w;
        q.x += x.x * x.x; q.y += x.y * x.y; q.z += x.z * x.z; q.w += x.w * x.w;
    }
    if (half) { ls[c4] = s; lq[c4] = q; }
    __syncthreads();
    if (!half) {
        float4 s2 = ls[c4], q2 = lq[c4];
        s.x += s2.x; s.y += s2.y; s.z += s2.z; s.w += s2.w;
        q.x += q2.x; q.y += q2.y; q.z += q2.z; q.w += q2.w;
        ((float4*)(ps + (size_t)blockIdx.x * N))[c4] = s;
        ((float4*)(pq + (size_t)blockIdx.x * N))[c4] = q;
    }
}

// ---------------- column stats, stage 2: reduce partials -> scale/shift ----------
__global__ __launch_bounds__(256) void colfin_kernel(const float* __restrict__ ps,
        const float* __restrict__ pq, const float* __restrict__ gamma,
        const float* __restrict__ beta, float* __restrict__ scale,
        float* __restrict__ shift, int npart, int N, int M) {
    int col = blockIdx.x * 256 + threadIdx.x;
    if (col >= N) return;
    float s = 0.f, q = 0.f;
    for (int k = 0; k < npart; ++k) {
        s += ps[(size_t)k * N + col];
        q += pq[(size_t)k * N + col];
    }
    float mean = s / M;
    float var = q / M - mean * mean;
    float sc = gamma[col] * rsqrtf(var + 1e-5f);
    scale[col] = sc;
    shift[col] = beta[col] - mean * sc;
}

// ---------------- apply BN (+ optional relu), emit bf16 ----------------
__global__ void bn_apply_kernel(const float* __restrict__ X, const float* __restrict__ scale,
        const float* __restrict__ shift, unsigned short* __restrict__ Y,
        int n4, int colmask4, int relu) {
    int stride = gridDim.x * blockDim.x;
    for (int i = blockIdx.x * blockDim.x + threadIdx.x; i < n4; i += stride) {
        float4 x = ((const float4*)X)[i];
        int c = (i & colmask4) * 4;
        float4 sc = *(const float4*)(scale + c);
        float4 sh = *(const float4*)(shift + c);
        float y0 = x.x * sc.x + sh.x;
        float y1 = x.y * sc.y + sh.y;
        float y2 = x.z * sc.z + sh.z;
        float y3 = x.w * sc.w + sh.w;
        if (relu) {
            y0 = fmaxf(y0, 0.f); y1 = fmaxf(y1, 0.f);
            y2 = fmaxf(y2, 0.f); y3 = fmaxf(y3, 0.f);
        }
        ushort4 o;
        o.x = f2bf(y0); o.y = f2bf(y1); o.z = f2bf(y2); o.w = f2bf(y3);
        ((ushort4*)Y)[i] = o;
    }
}

// ---------------- bf16 GEMM: 8-wave, swizzled LDS, frag-double-buffered (R8/R15) --
// Used for gemm1 only.
template <bool FUSE>
__global__ __launch_bounds__(512) void gemm8w_kernel(const unsigned short* __restrict__ A,
        const unsigned short* __restrict__ W, const float* __restrict__ bias,
        float* __restrict__ out, const float* __restrict__ lin,
        const float* __restrict__ gb, float* __restrict__ out0,
        int M, int N, int K) {
    __shared__ short As[3 * 4096];
    __shared__ short Bs[3 * 4096];
    int tid = threadIdx.x;
    int lane = tid & 63, w = tid >> 6;
    int wr = w >> 2, wc = w & 3;
    int l15 = lane & 15, lhi = lane >> 4;
    int xk = (l15 >> 1) & 3;
    int rchunk = (lhi ^ xk) << 3;

    int nwg = gridDim.x * gridDim.y;
    int bid = blockIdx.y * gridDim.x + blockIdx.x;
    int s = (bid & 7) * (nwg >> 3) + (bid >> 3);
    int gsz = gridDim.x << 3;
    int g = s / gsz, r = s % gsz;
    int by = (g << 3) + (r & 7);
    int bx = r >> 3;
    int bm = by * 128, bn = bx * 128;

    int rA = tid >> 2;
    int kp = tid & 3;
    int kps = kp ^ ((rA >> 1) & 3);
    const unsigned short* gA = A + (size_t)(bm + rA) * K + kps * 8;
    const unsigned short* gB = W + (size_t)(bn + rA) * K + kps * 8;

    f32x4 acc[4][2];
#pragma unroll
    for (int i = 0; i < 4; ++i)
#pragma unroll
        for (int j = 0; j < 2; ++j) { f32x4 z = {0.f, 0.f, 0.f, 0.f}; acc[i][j] = z; }

    auto STAGE = [&](int t, int buf) {
        int k0 = t << 5;
        glds16(gA + k0, (char*)(As + buf * 4096) + w * 1024);
        glds16(gB + k0, (char*)(Bs + buf * 4096) + w * 1024);
    };
    auto LOADF = [&](bf16x8* af, bf16x8* bv, int buf) {
        const short* Ab = As + buf * 4096;
        const short* Bb = Bs + buf * 4096;
#pragma unroll
        for (int mi = 0; mi < 4; ++mi)
            af[mi] = *(const bf16x8*)&Ab[(wr * 64 + mi * 16 + l15) * 32 + rchunk];
#pragma unroll
        for (int ni = 0; ni < 2; ++ni)
            bv[ni] = *(const bf16x8*)&Bb[(wc * 32 + ni * 16 + l15) * 32 + rchunk];
    };
    auto MFMA8 = [&](const bf16x8* af, const bf16x8* bv) {
#pragma unroll
        for (int mi = 0; mi < 4; ++mi)
#pragma unroll
            for (int ni = 0; ni < 2; ++ni)
                acc[mi][ni] = __builtin_amdgcn_mfma_f32_16x16x32_bf16(af[mi], bv[ni], acc[mi][ni], 0, 0, 0);
    };

    int NT = K >> 5;

    STAGE(0, 0);
    STAGE(1, 1);
    asm volatile("s_waitcnt vmcnt(2)" ::: "memory");
    __builtin_amdgcn_sched_barrier(0);
    __builtin_amdgcn_s_barrier();
    __builtin_amdgcn_sched_barrier(0);

    bf16x8 afA[4], bvA[2], afB[4], bvB[2];
    LOADF(afA, bvA, 0);

    for (int t = 0; t + 4 <= NT; t += 2) {
        STAGE(t + 2, (t + 2) % 3);
        asm volatile("s_waitcnt lgkmcnt(0)" ::: "memory");
        __builtin_amdgcn_sched_barrier(0);
        asm volatile("s_waitcnt vmcnt(2)" ::: "memory");
        __builtin_amdgcn_sched_barrier(0);
        __builtin_amdgcn_s_barrier();
        __builtin_amdgcn_sched_barrier(0);
        LOADF(afB, bvB, (t + 1) % 3);
        __builtin_amdgcn_s_setprio(1);
        MFMA8(afA, bvA);
        __builtin_amdgcn_s_setprio(0);
        __builtin_amdgcn_sched_group_barrier(0x100, 6, 0);
        __builtin_amdgcn_sched_group_barrier(0x008, 8, 0);
        STAGE(t + 3, (t + 3) % 3);
        asm volatile("s_waitcnt lgkmcnt(0)" ::: "memory");
        __builtin_amdgcn_sched_barrier(0);
        asm volatile("s_waitcnt vmcnt(2)" ::: "memory");
        __builtin_amdgcn_sched_barrier(0);
        __builtin_amdgcn_s_barrier();
        __builtin_amdgcn_sched_barrier(0);
        LOADF(afA, bvA, (t + 2) % 3);
        __builtin_amdgcn_s_setprio(1);
        MFMA8(afB, bvB);
        __builtin_amdgcn_s_setprio(0);
        __builtin_amdgcn_sched_group_barrier(0x100, 6, 0);
        __builtin_amdgcn_sched_group_barrier(0x008, 8, 0);
    }
    asm volatile("s_waitcnt lgkmcnt(0)" ::: "memory");
    __builtin_amdgcn_sched_barrier(0);
    asm volatile("s_waitcnt vmcnt(0)" ::: "memory");
    __builtin_amdgcn_sched_barrier(0);
    __builtin_amdgcn_s_barrier();
    __builtin_amdgcn_sched_barrier(0);
    LOADF(afB, bvB, (NT - 1) % 3);
    __builtin_amdgcn_s_setprio(1);
    MFMA8(afA, bvA);
    __builtin_amdgcn_s_setprio(0);
    asm volatile("s_waitcnt lgkmcnt(0)" ::: "memory");
    __builtin_amdgcn_sched_barrier(0);
    __builtin_amdgcn_s_setprio(1);
    MFMA8(afB, bvB);
    __builtin_amdgcn_s_setprio(0);

#pragma unroll
    for (int mi = 0; mi < 4; ++mi)
#pragma unroll
        for (int ni = 0; ni < 2; ++ni) {
            int col = bn + wc * 32 + ni * 16 + l15;
            float bb = bias[col];
            float gbv = FUSE ? gb[col] : 0.f;
            int row0 = bm + wr * 64 + mi * 16 + lhi * 4;
#pragma unroll
            for (int r2 = 0; r2 < 4; ++r2) {
                size_t idx = (size_t)(row0 + r2) * N + col;
                float v = acc[mi][ni][r2] + bb;
                out[idx] = v;
                if (FUSE) out0[idx] = gbv + lin[idx] + v;
            }
        }
}

// ---------------- 256x128 GEMM: 1-barrier iter, 4 counted-lgkm waypoints (R19) ---
template <bool FUSE>
__global__ __launch_bounds__(512) void gemm256_kernel(const unsigned short* __restrict__ A,
        const unsigned short* __restrict__ W, const float* __restrict__ bias,
        float* __restrict__ out, const float* __restrict__ lin,
        const float* __restrict__ gb, float* __restrict__ out0,
        int M, int N, int K) {
    __shared__ short As[3 * 16384];   // 3 x 256x64 = 96 KB
    __shared__ short Bs[3 * 8192];    // 3 x 128x64 = 48 KB
    int tid = threadIdx.x;
    int l = tid & 63, w = tid >> 6;
    int wm = w >> 1, wn = w & 1;
    int l15 = l & 15, lhi = l >> 4;
    int lr = l >> 3, lc = l & 7;
    int sc = lc ^ lr;                     // pre-swizzled source chunk

    int bid = blockIdx.y * gridDim.x + blockIdx.x;
    int s = (bid & 7) * ((gridDim.x * gridDim.y) >> 3) + (bid >> 3);
    int by = s & 7, bx = s >> 3;
    int bm = by * 256, bn = bx * 128;

    const unsigned short* gA0 = A + (size_t)(bm +   0 + w * 8 + lr) * K + sc * 8;
    const unsigned short* gA1 = A + (size_t)(bm +  64 + w * 8 + lr) * K + sc * 8;
    const unsigned short* gA2 = A + (size_t)(bm + 128 + w * 8 + lr) * K + sc * 8;
    const unsigned short* gA3 = A + (size_t)(bm + 192 + w * 8 + lr) * K + sc * 8;
    const unsigned short* gB0 = W + (size_t)(bn +   0 + w * 8 + lr) * K + sc * 8;
    const unsigned short* gB1 = W + (size_t)(bn +  64 + w * 8 + lr) * K + sc * 8;

    int xk7 = l15 & 7;
    int aR0 = (wm * 64 +  0 + l15) << 7;
    int aR1 = (wm * 64 + 16 + l15) << 7;
    int aR2 = (wm * 64 + 32 + l15) << 7;
    int aR3 = (wm * 64 + 48 + l15) << 7;
    int bR0 = (wn * 64 +  0 + l15) << 7;
    int bR1 = (wn * 64 + 16 + l15) << 7;
    int bR2 = (wn * 64 + 32 + l15) << 7;
    int bR3 = (wn * 64 + 48 + l15) << 7;
    int c0 = ((0 + lhi) ^ xk7) << 4;
    int c1 = ((4 + lhi) ^ xk7) << 4;

    f32x4 acc[4][4];
#pragma unroll
    for (int i = 0; i < 4; ++i)
#pragma unroll
        for (int j = 0; j < 4; ++j) { f32x4 z = {0.f, 0.f, 0.f, 0.f}; acc[i][j] = z; }

    const char* AsB = (const char*)As;
    const char* BsB = (const char*)Bs;
#define RDA(rr, cc, bo) (*(const bf16x8*)(AsB + (bo) + (rr) + (cc)))
#define RDB(rr, cc, bo) (*(const bf16x8*)(BsB + (bo) + (rr) + (cc)))
#define MM(x, y, ai, bi_) acc[ai][bi_] = __builtin_amdgcn_mfma_f32_16x16x32_bf16(x, y, acc[ai][bi_], 0, 0, 0);

    bf16x8 a0, a1, a2, a3, b0, b1, b2, b3;
    bf16x8 a4, a5, a6, a7, b4, b5, b6, b7;
#define SB    __builtin_amdgcn_sched_barrier(0);
#define BAR   { __builtin_amdgcn_s_barrier(); SB }

    int NT = K >> 6;

    {
        int dA = w * 1024;
        glds16(gA0, (char*)As + dA);           glds16(gA1, (char*)As + 8192 + dA);
        glds16(gA2, (char*)As + 16384 + dA);   glds16(gA3, (char*)As + 24576 + dA);
        glds16(gB0, (char*)Bs + dA);           glds16(gB1, (char*)Bs + 8192 + dA);
        glds16(gA0 + 64, (char*)As + 32768 + dA);         glds16(gA1 + 64, (char*)As + 32768 + 8192 + dA);
        glds16(gA2 + 64, (char*)As + 32768 + 16384 + dA); glds16(gA3 + 64, (char*)As + 32768 + 24576 + dA);
        glds16(gB0 + 64, (char*)Bs + 16384 + dA);         glds16(gB1 + 64, (char*)Bs + 16384 + 8192 + dA);
    }
    asm volatile("s_waitcnt vmcnt(6)" ::: "memory");
    SB
    BAR;

    int cur = 0;
    for (int t = 0; t < NT; ++t) {
        int s2 = cur + 2; if (s2 >= 3) s2 -= 3;
        int Abo = cur * 32768, Bbo = cur * 16384;
        int AboS = s2 * 32768, BboS = s2 * 16384;
        int kst = (t + 2) << 6;
        bool st = (t + 2) < NT;
        int dA = w * 1024;

        a0 = RDA(aR0, c0, Abo); a1 = RDA(aR1, c0, Abo);
        b0 = RDB(bR0, c0, Bbo); b1 = RDB(bR1, c0, Bbo);
        SB
        a2 = RDA(aR2, c0, Abo); a3 = RDA(aR3, c0, Abo);
        b2 = RDB(bR2, c0, Bbo); b3 = RDB(bR3, c0, Bbo);
        SB
        a4 = RDA(aR0, c1, Abo); a5 = RDA(aR1, c1, Abo);
        b4 = RDB(bR0, c1, Bbo); b5 = RDB(bR1, c1, Bbo);
        SB
        a6 = RDA(aR2, c1, Abo); a7 = RDA(aR3, c1, Abo);
        b6 = RDB(bR2, c1, Bbo); b7 = RDB(bR3, c1, Bbo);
        SB
        if (st) {
            glds16(gA0 + kst, (char*)As + AboS + dA);
            glds16(gA1 + kst, (char*)As + AboS + 8192 + dA);
            glds16(gA2 + kst, (char*)As + AboS + 16384 + dA);
            glds16(gA3 + kst, (char*)As + AboS + 24576 + dA);
            glds16(gB0 + kst, (char*)Bs + BboS + dA);
            glds16(gB1 + kst, (char*)Bs + BboS + 8192 + dA);
        }
        SB
        asm volatile("s_waitcnt lgkmcnt(12)" ::: "memory"); SB
        __builtin_amdgcn_s_setprio(1);
        MM(a0, b0, 0, 0) MM(a0, b1, 0, 1) MM(a1, b0, 1, 0) MM(a1, b1, 1, 1)
        __builtin_amdgcn_s_setprio(0); SB
        asm volatile("s_waitcnt lgkmcnt(8)" ::: "memory"); SB
        __builtin_amdgcn_s_setprio(1);
        MM(a2, b0, 2, 0) MM(a2, b1, 2, 1) MM(a3, b0, 3, 0) MM(a3, b1, 3, 1)
        MM(a0, b2, 0, 2) MM(a0, b3, 0, 3) MM(a1, b2, 1, 2) MM(a1, b3, 1, 3)
        MM(a2, b2, 2, 2) MM(a2, b3, 2, 3) MM(a3, b2, 3, 2) MM(a3, b3, 3, 3)
        __builtin_amdgcn_s_setprio(0); SB
        asm volatile("s_waitcnt lgkmcnt(4)" ::: "memory"); SB
        __builtin_amdgcn_s_setprio(1);
        MM(a4, b4, 0, 0) MM(a4, b5, 0, 1) MM(a5, b4, 1, 0) MM(a5, b5, 1, 1)
        __builtin_amdgcn_s_setprio(0); SB
        asm volatile("s_waitcnt lgkmcnt(0)" ::: "memory"); SB
        __builtin_amdgcn_s_setprio(1);
        MM(a6, b4, 2, 0) MM(a6, b5, 2, 1) MM(a7, b4, 3, 0) MM(a7, b5, 3, 1)
        MM(a4, b6, 0, 2) MM(a4, b7, 0, 3) MM(a5, b6, 1, 2) MM(a5, b7, 1, 3)
        MM(a6, b6, 2, 2) MM(a6, b7, 2, 3) MM(a7, b6, 3, 2) MM(a7, b7, 3, 3)
        __builtin_amdgcn_s_setprio(0);
        if (t + 1 < NT) {
            if (t + 2 < NT) { asm volatile("s_waitcnt vmcnt(6)" ::: "memory"); }
            else            { asm volatile("s_waitcnt vmcnt(0)" ::: "memory"); }
            SB
            BAR;
        }
        ++cur; if (cur >= 3) cur = 0;
    }
#undef RDA
#undef RDB
#undef MM
#undef SB
#undef BAR

#pragma unroll
    for (int mi = 0; mi < 4; ++mi)
#pragma unroll
        for (int ni = 0; ni < 4; ++ni) {
            int col = bn + wn * 64 + ni * 16 + l15;
            float bb = bias[col];
            float gbv = FUSE ? gb[col] : 0.f;
            int row0 = bm + wm * 64 + mi * 16 + lhi * 4;
#pragma unroll
            for (int r2 = 0; r2 < 4; ++r2) {
                size_t idx = (size_t)(row0 + r2) * N + col;
                float v = acc[mi][ni][r2] + bb;
                out[idx] = v;
                if (FUSE) out0[idx] = gbv + lin[idx] + v;
            }
        }
}

extern "C" void kernel_launch(void* const* d_in, const int* in_sizes, int n_in,
                              void* d_out, int out_size, void* d_ws, size_t ws_size,
                              hipStream_t stream) {
    const float* sae  = (const float*)d_in[0];
    const float* emb  = (const float*)d_in[1];
    const float* lin_w = (const float*)d_in[2];
    const float* lin_b = (const float*)d_in[3];
    const float* gbias = (const float*)d_in[4];
    const float* bn1g = (const float*)d_in[5];
    const float* bn1b = (const float*)d_in[6];
    const float* w1   = (const float*)d_in[7];
    const float* b1   = (const float*)d_in[8];
    const float* bn2g = (const float*)d_in[9];
    const float* bn2b = (const float*)d_in[10];
    const float* w2   = (const float*)d_in[11];
    const float* b2   = (const float*)d_in[12];
    float* out = (float*)d_out;
    const size_t BO = (size_t)B_ * O_;

    char* ws = (char*)d_ws;
    auto alloc = [&](size_t bytes) -> char* {
        char* p = ws;
        ws += (bytes + 255) & ~(size_t)255;
        return p;
    };
    unsigned short* sae_bf  = (unsigned short*)alloc((size_t)B_ * F_ * 2);  // 64 MB
    unsigned short* linw_bf = (unsigned short*)alloc((size_t)O_ * F_ * 2);  // 128 MB
    unsigned short* w1_bf   = (unsigned short*)alloc((size_t)D_ * D_ * 2);
    unsigned short* w2_bf   = (unsigned short*)alloc((size_t)O_ * D_ * 2);
    unsigned short* a1_bf   = (unsigned short*)alloc((size_t)B_ * D_ * 2);
    unsigned short* h2_bf   = (unsigned short*)alloc((size_t)B_ * D_ * 2);
    ull*   cand = (ull*)alloc((size_t)B_ * 160 * 8);
    float* bi = (float*)alloc((size_t)B_ * D_ * 4);
    float* h1 = (float*)alloc((size_t)B_ * D_ * 4);
    float* ps = (float*)alloc(64 * D_ * 4);
    float* pq = (float*)alloc(64 * D_ * 4);
    float* sc1 = (float*)alloc(D_ * 4);
    float* sh1 = (float*)alloc(D_ * 4);
    float* sc2 = (float*)alloc(D_ * 4);
    float* sh2 = (float*)alloc(D_ * 4);

    // fused front: top-k phase 1 + ALL weight conversions (one HBM-bound dispatch)
    fused_front_kernel<<<TOPK_BLKS + CVT_BLKS, 256, 0, stream>>>(
        sae, cand, sae_bf, lin_w, linw_bf, w1, w1_bf, w2, w2_bf);

    // bi-interaction pooling (fused exact top-20 rank-select)
    bi_kernel<<<B_, 256, 0, stream>>>(cand, emb, bi);

    // BN1 -> bf16, GEMM1
    colpart_kernel<<<64, 256, 0, stream>>>(bi, ps, pq, D_);
    colfin_kernel<<<2, 256, 0, stream>>>(ps, pq, bn1g, bn1b, sc1, sh1, 64, D_, B_);
    bn_apply_kernel<<<1024, 256, 0, stream>>>(bi, sc1, sh1, a1_bf, B_ * D_ / 4, D_ / 4 - 1, 0);
    gemm8w_kernel<false><<<dim3(D_ / 128, B_ / 128), 512, 0, stream>>>(
        a1_bf, w1_bf, b1, h1, nullptr, nullptr, nullptr, B_, D_, D_);

    // BN2 + relu -> bf16
    colpart_kernel<<<64, 256, 0, stream>>>(h1, ps, pq, D_);
    colfin_kernel<<<2, 256, 0, stream>>>(ps, pq, bn2g, bn2b, sc2, sh2, 64, D_, B_);
    bn_apply_kernel<<<1024, 256, 0, stream>>>(h1, sc2, sh2, h2_bf, B_ * D_ / 4, D_ / 4 - 1, 1);

    // big GEMM (256x128, waypointed counted-lgkm, full K) -> linear_out (+lin_b)
    gemm256_kernel<false><<<dim3(O_ / 128, B_ / 256), 512, 0, stream>>>(
        sae_bf, linw_bf, lin_b, out + BO, nullptr, nullptr, nullptr, B_, O_, F_);

    // GEMM2 (same structure, K=512) -> interaction_out, fused final combine:
    //   out0 = global_bias + linear_out + interaction_out
    gemm256_kernel<true><<<dim3(O_ / 128, B_ / 256), 512, 0, stream>>>(
        h2_bf, w2_bf, b2, out + 2 * BO, out + BO, gbias, out, B_, O_, D_);
}